// Round 7
// baseline (44.853 us; speedup 1.0000x reference)
//
#include <hip/hip_runtime.h>

// inputs (8, 512, 96, 2) f32, WIN=10. Output (8, 511, 96, 96) f32 = 150.7 MB.
constexpr int WIN = 10;
constexpr int Bn  = 8;
constexpr int Sn  = 512;
constexpr int An  = 96;
constexpr int Tn  = Sn - 1;          // 511
constexpr int AV  = An * 2;          // 192

constexpr int SCHUNK = 32;           // s-rows per partial-sum block
constexpr int NCH    = Sn / SCHUNK;  // 16
constexpr int CH     = 16;           // t-outputs per corr block
constexpr int CHUNKS_PER_B = (Tn + CH - 1) / CH;   // 32
constexpr int MAXROWS = CH + WIN - 1;              // 25 staged s-rows
constexpr int ISPLIT  = 4;                         // i-rows split across blocks
constexpr int ROWS    = An / ISPLIT;               // 24 rows per block
constexpr int NTHR    = 192;
constexpr int TXN     = 24;          // float4-column index 0..23  (j = 4*tx+c)
constexpr int TYN     = NTHR / TXN;  // 8
constexpr int RPT     = ROWS / TYN;  // 3 rows per thread

typedef float vfloat4 __attribute__((ext_vector_type(4)));

// ---- mean pass: partial sums over 32-s chunks (coalesced) ----
__global__ __launch_bounds__(192)
void partial_kernel(const float* __restrict__ in, float* __restrict__ partial) {
    const int blk = blockIdx.x;              // b * NCH + c
    const int b   = blk / NCH;
    const int c   = blk - b * NCH;
    const int av  = threadIdx.x;             // 0..191
    const float* p = in + ((size_t)(b * Sn + c * SCHUNK)) * AV + av;
    float acc = 0.f;
    #pragma unroll
    for (int s = 0; s < SCHUNK; ++s) acc += p[(size_t)s * AV];
    partial[(size_t)blk * AV + av] = acc;
}

// ---- corr: one block per (b, 16-t chunk, i-quarter) ----
__global__ __launch_bounds__(192)
void corr_kernel(const float* __restrict__ in, const float* __restrict__ partial,
                 float* __restrict__ out) {
    __shared__ __align__(16) float xw[MAXROWS * AV];  // 18.75 KB
    __shared__ __align__(16) float smu[AV];

    const int bid     = blockIdx.x;
    const int b       = bid / (CHUNKS_PER_B * ISPLIT);
    const int rem     = bid - b * (CHUNKS_PER_B * ISPLIT);
    const int chunk   = rem >> 2;            // ISPLIT == 4
    const int quarter = rem & 3;
    const int i0      = quarter * ROWS;

    const int t0 = chunk * CH;
    const int t1 = min(t0 + CH - 1, Tn - 1);
    int sbase = t0 - (WIN - 1); if (sbase < 0) sbase = 0;
    const int nrows = t1 - sbase + 1;        // <= 25

    const int tid = threadIdx.x;

    // --- reduce 16 partials -> mean, in LDS ---
    {
        const float* pp = partial + (size_t)b * NCH * AV + tid;
        float acc = 0.f;
        #pragma unroll
        for (int c = 0; c < NCH; ++c) acc += pp[(size_t)c * AV];
        smu[tid] = acc * (1.0f / Sn);
    }
    __syncthreads();

    // --- stage rows [sbase..t1], centered, float4-vectorized ---
    {
        const float4* src = reinterpret_cast<const float4*>(
            in + ((size_t)(b * Sn + sbase)) * AV);
        const float4* mb4 = reinterpret_cast<const float4*>(smu);
        float4* dst = reinterpret_cast<float4*>(xw);
        const int tot4 = nrows * (AV / 4);
        for (int idx = tid; idx < tot4; idx += NTHR) {
            int av4 = idx % (AV / 4);
            float4 v = src[idx], m = mb4[av4];
            v.x -= m.x; v.y -= m.y; v.z -= m.z; v.w -= m.w;
            dst[idx] = v;
        }
    }
    __syncthreads();

    const int tx = tid % TXN;   // float4 col: j = 4*tx + c
    const int ty = tid / TXN;   // row group: i = i0 + ty + 8*r

    float acc[RPT][4];
    float di[RPT], dj[4];
    #pragma unroll
    for (int r = 0; r < RPT; ++r) {
        di[r] = 0.f;
        #pragma unroll
        for (int c = 0; c < 4; ++c) acc[r][c] = 0.f;
    }
    #pragma unroll
    for (int c = 0; c < 4; ++c) dj[c] = 0.f;

#define ACCUM(ls, OP)                                                        \
    {                                                                        \
        const float* xs = &xw[(ls) * AV];                                    \
        float4 xj0 = *reinterpret_cast<const float4*>(&xs[8 * tx]);          \
        float4 xj1 = *reinterpret_cast<const float4*>(&xs[8 * tx + 4]);      \
        dj[0] OP (xj0.x * xj0.x + xj0.y * xj0.y);                            \
        dj[1] OP (xj0.z * xj0.z + xj0.w * xj0.w);                            \
        dj[2] OP (xj1.x * xj1.x + xj1.y * xj1.y);                            \
        dj[3] OP (xj1.z * xj1.z + xj1.w * xj1.w);                            \
        _Pragma("unroll")                                                    \
        for (int r = 0; r < RPT; ++r) {                                      \
            float2 xi = *reinterpret_cast<const float2*>(                    \
                &xs[(i0 + ty + 8 * r) * 2]);                                 \
            di[r] OP (xi.x * xi.x + xi.y * xi.y);                            \
            acc[r][0] OP (xi.x * xj0.x + xi.y * xj0.y);                      \
            acc[r][1] OP (xi.x * xj0.z + xi.y * xj0.w);                      \
            acc[r][2] OP (xi.x * xj1.x + xi.y * xj1.y);                      \
            acc[r][3] OP (xi.x * xj1.z + xi.y * xj1.w);                      \
        }                                                                    \
    }

    // normalize + mask + store one t — NONTEMPORAL float4 stores (bypass L2)
    auto emit = [&](int t) {
        float rsj[4];
        #pragma unroll
        for (int c = 0; c < 4; ++c) rsj[c] = rsqrtf(dj[c]);
        float* ob = out + (size_t)(b * Tn + t) * (An * An);
        #pragma unroll
        for (int r = 0; r < RPT; ++r) {
            int i = i0 + ty + 8 * r;
            float ri = rsqrtf(di[r]);
            vfloat4 v;
            v.x = (i == 4 * tx + 0) ? 0.f : acc[r][0] * ri * rsj[0];
            v.y = (i == 4 * tx + 1) ? 0.f : acc[r][1] * ri * rsj[1];
            v.z = (i == 4 * tx + 2) ? 0.f : acc[r][2] * ri * rsj[2];
            v.w = (i == 4 * tx + 3) ? 0.f : acc[r][3] * ri * rsj[3];
            __builtin_nontemporal_store(
                v, reinterpret_cast<vfloat4*>(&ob[(size_t)i * An + 4 * tx]));
        }
    };

    // --- warm-up: full window sum for t0 ---
    for (int s = sbase; s <= t0; ++s) ACCUM(s - sbase, +=);
    emit(t0);

    // --- slide: W(t) = W(t-1) + g(t) - g(t-WIN) ---
    for (int t = t0 + 1; t <= t1; ++t) {
        ACCUM(t - sbase, +=);
        if (t >= WIN) ACCUM(t - WIN - sbase, -=);
        emit(t);
    }
#undef ACCUM
}

extern "C" void kernel_launch(void* const* d_in, const int* in_sizes, int n_in,
                              void* d_out, int out_size, void* d_ws, size_t ws_size,
                              hipStream_t stream) {
    const float* in = (const float*)d_in[0];
    float* out = (float*)d_out;
    float* partial = (float*)d_ws;    // Bn*NCH*AV = 24576 floats

    partial_kernel<<<Bn * NCH, 192, 0, stream>>>(in, partial);
    corr_kernel<<<Bn * CHUNKS_PER_B * ISPLIT, NTHR, 0, stream>>>(in, partial, out);
}

// Round 8
// 42.452 us; speedup vs baseline: 1.0566x; 1.0566x over previous
//
#include <hip/hip_runtime.h>

// inputs (8, 512, 96, 2) f32, WIN=10. Output (8, 511, 96, 96) f32 = 150.7 MB.
constexpr int WIN = 10;
constexpr int Bn  = 8;
constexpr int Sn  = 512;
constexpr int An  = 96;
constexpr int Tn  = Sn - 1;          // 511
constexpr int AV  = An * 2;          // 192

constexpr int SCHUNK = 32;           // s-rows per partial-sum block
constexpr int NCH    = Sn / SCHUNK;  // 16
constexpr int CH     = 16;           // t-outputs per corr block
constexpr int CHUNKS_PER_B = (Tn + CH - 1) / CH;   // 32
constexpr int MAXROWS = CH + WIN - 1;              // 25 staged s-rows
constexpr int ISPLIT  = 4;                         // i-rows split across blocks
constexpr int ROWS    = An / ISPLIT;               // 24 rows per block
constexpr int NTHR    = 192;
constexpr int TXN     = 24;          // float4-column index 0..23  (j = 4*tx+c)
constexpr int TYN     = NTHR / TXN;  // 8
constexpr int RPT     = ROWS / TYN;  // 3 rows per thread

// Swizzled LDS row: 6 superblocks of (32 data floats + 4 pad) = 216 floats.
// float f (0..191) lives at (f/32)*36 + (f%32).  16B alignment preserved.
constexpr int SWR = 216;             // floats per swizzled row
__device__ __forceinline__ int swoff(int f) { return (f >> 5) * 36 + (f & 31); }

// ---- mean pass: partial sums over 32-s chunks (coalesced) ----
__global__ __launch_bounds__(192)
void partial_kernel(const float* __restrict__ in, float* __restrict__ partial) {
    const int blk = blockIdx.x;              // b * NCH + c
    const int b   = blk / NCH;
    const int c   = blk - b * NCH;
    const int av  = threadIdx.x;             // 0..191
    const float* p = in + ((size_t)(b * Sn + c * SCHUNK)) * AV + av;
    float acc = 0.f;
    #pragma unroll
    for (int s = 0; s < SCHUNK; ++s) acc += p[(size_t)s * AV];
    partial[(size_t)blk * AV + av] = acc;
}

// ---- corr: one block per (b, 16-t chunk, i-quarter) ----
__global__ __launch_bounds__(192)
void corr_kernel(const float* __restrict__ in, const float* __restrict__ partial,
                 float* __restrict__ out) {
    __shared__ __align__(16) float xw[MAXROWS * SWR]; // 21.6 KB swizzled rows
    __shared__ __align__(16) float rs[CH][An];        // rsqrt of sliding diag
    __shared__ __align__(16) float smu[AV];

    const int bid     = blockIdx.x;
    const int b       = bid / (CHUNKS_PER_B * ISPLIT);
    const int rem     = bid - b * (CHUNKS_PER_B * ISPLIT);
    const int chunk   = rem >> 2;            // ISPLIT == 4
    const int quarter = rem & 3;
    const int i0      = quarter * ROWS;

    const int t0 = chunk * CH;
    const int t1 = min(t0 + CH - 1, Tn - 1);
    int sbase = t0 - (WIN - 1); if (sbase < 0) sbase = 0;
    const int nrows = t1 - sbase + 1;        // <= 25

    const int tid = threadIdx.x;

    // --- reduce 16 partials -> mean, in LDS ---
    {
        const float* pp = partial + (size_t)b * NCH * AV + tid;
        float acc = 0.f;
        #pragma unroll
        for (int c = 0; c < NCH; ++c) acc += pp[(size_t)c * AV];
        smu[tid] = acc * (1.0f / Sn);
    }
    __syncthreads();

    // --- stage rows [sbase..t1], centered, float4 into swizzled layout ---
    {
        const float4* src = reinterpret_cast<const float4*>(
            in + ((size_t)(b * Sn + sbase)) * AV);
        const float4* mb4 = reinterpret_cast<const float4*>(smu);
        float4* dst = reinterpret_cast<float4*>(xw);
        const int tot4 = nrows * (AV / 4);
        for (int idx = tid; idx < tot4; idx += NTHR) {
            int row = idx / (AV / 4);
            int q   = idx - row * (AV / 4);      // float4 index within row
            float4 v = src[idx], m = mb4[q];
            v.x -= m.x; v.y -= m.y; v.z -= m.z; v.w -= m.w;
            dst[row * (SWR / 4) + (q >> 3) * 9 + (q & 7)] = v;
        }
    }
    __syncthreads();

    // --- sliding diagonal -> rsqrt, once per block (threads 0..95) ---
    if (tid < An) {
        const int off = swoff(2 * tid);
        float d = 0.f;
        for (int s = sbase; s <= t0; ++s) {
            float x0 = xw[(s - sbase) * SWR + off];
            float x1 = xw[(s - sbase) * SWR + off + 1];
            d += x0 * x0 + x1 * x1;
        }
        rs[0][tid] = rsqrtf(d);
        for (int t = t0 + 1; t <= t1; ++t) {
            float x0 = xw[(t - sbase) * SWR + off];
            float x1 = xw[(t - sbase) * SWR + off + 1];
            d += x0 * x0 + x1 * x1;
            if (t >= WIN) {
                float y0 = xw[(t - WIN - sbase) * SWR + off];
                float y1 = xw[(t - WIN - sbase) * SWR + off + 1];
                d -= y0 * y0 + y1 * y1;
            }
            rs[t - t0][tid] = rsqrtf(d);
        }
    }
    __syncthreads();

    const int tx = tid % TXN;   // float4 col: j = 4*tx + c
    const int ty = tid / TXN;   // row group: i = i0 + ty + 8*r
    const int oj = swoff(8 * tx);                 // xj float offset in row
    int oi[RPT];
    #pragma unroll
    for (int r = 0; r < RPT; ++r) oi[r] = swoff(2 * (i0 + ty + 8 * r));

    float acc[RPT][4];
    #pragma unroll
    for (int r = 0; r < RPT; ++r)
        #pragma unroll
        for (int c = 0; c < 4; ++c) acc[r][c] = 0.f;

#define ACCUM(ls, OP)                                                        \
    {                                                                        \
        const float* xs = &xw[(ls) * SWR];                                   \
        float4 xj0 = *reinterpret_cast<const float4*>(&xs[oj]);              \
        float4 xj1 = *reinterpret_cast<const float4*>(&xs[oj + 4]);          \
        _Pragma("unroll")                                                    \
        for (int r = 0; r < RPT; ++r) {                                      \
            float2 xi = *reinterpret_cast<const float2*>(&xs[oi[r]]);        \
            acc[r][0] OP (xi.x * xj0.x + xi.y * xj0.y);                      \
            acc[r][1] OP (xi.x * xj0.z + xi.y * xj0.w);                      \
            acc[r][2] OP (xi.x * xj1.x + xi.y * xj1.y);                      \
            acc[r][3] OP (xi.x * xj1.z + xi.y * xj1.w);                      \
        }                                                                    \
    }

    // normalize + mask + store one t (rsqrt's precomputed in rs[][])
    auto emit = [&](int t) {
        const int tt = t - t0;
        float4 rsj = *reinterpret_cast<const float4*>(&rs[tt][4 * tx]);
        float* ob = out + (size_t)(b * Tn + t) * (An * An);
        #pragma unroll
        for (int r = 0; r < RPT; ++r) {
            int i = i0 + ty + 8 * r;
            float ri = rs[tt][i];
            float4 v;
            v.x = (i == 4 * tx + 0) ? 0.f : acc[r][0] * ri * rsj.x;
            v.y = (i == 4 * tx + 1) ? 0.f : acc[r][1] * ri * rsj.y;
            v.z = (i == 4 * tx + 2) ? 0.f : acc[r][2] * ri * rsj.z;
            v.w = (i == 4 * tx + 3) ? 0.f : acc[r][3] * ri * rsj.w;
            *reinterpret_cast<float4*>(&ob[(size_t)i * An + 4 * tx]) = v;
        }
    };

    // --- warm-up: full window sum for t0 ---
    for (int s = sbase; s <= t0; ++s) ACCUM(s - sbase, +=);
    emit(t0);

    // --- slide: W(t) = W(t-1) + g(t) - g(t-WIN) ---
    for (int t = t0 + 1; t <= t1; ++t) {
        ACCUM(t - sbase, +=);
        if (t >= WIN) ACCUM(t - WIN - sbase, -=);
        emit(t);
    }
#undef ACCUM
}

extern "C" void kernel_launch(void* const* d_in, const int* in_sizes, int n_in,
                              void* d_out, int out_size, void* d_ws, size_t ws_size,
                              hipStream_t stream) {
    const float* in = (const float*)d_in[0];
    float* out = (float*)d_out;
    float* partial = (float*)d_ws;    // Bn*NCH*AV = 24576 floats

    partial_kernel<<<Bn * NCH, 192, 0, stream>>>(in, partial);
    corr_kernel<<<Bn * CHUNKS_PER_B * ISPLIT, NTHR, 0, stream>>>(in, partial, out);
}

// Round 9
// 42.097 us; speedup vs baseline: 1.0655x; 1.0084x over previous
//
#include <hip/hip_runtime.h>

// inputs (8, 512, 96, 2) f32, WIN=10. Output (8, 511, 96, 96) f32 = 150.7 MB.
constexpr int WIN = 10;
constexpr int Bn  = 8;
constexpr int Sn  = 512;
constexpr int An  = 96;
constexpr int Tn  = Sn - 1;          // 511
constexpr int AV  = An * 2;          // 192

constexpr int SCHUNK = 32;           // s-rows per partial-sum block
constexpr int NCH    = Sn / SCHUNK;  // 16
constexpr int CH     = 32;           // t-outputs per corr block
constexpr int CHUNKS_PER_B = (Tn + CH - 1) / CH;   // 16
constexpr int MAXROWS = CH + WIN - 1;              // 41 staged s-rows
constexpr int ISPLIT  = 4;                         // i-rows split across blocks
constexpr int ROWS    = An / ISPLIT;               // 24 rows per block
constexpr int NTHR    = 192;
constexpr int TXN     = 24;          // float4-column index 0..23  (j = 4*tx+c)
constexpr int TYN     = NTHR / TXN;  // 8
constexpr int RPT     = ROWS / TYN;  // 3 rows per thread

// ---- mean pass: partial sums over 32-s chunks (coalesced) ----
__global__ __launch_bounds__(192)
void partial_kernel(const float* __restrict__ in, float* __restrict__ partial) {
    const int blk = blockIdx.x;              // b * NCH + c
    const int b   = blk / NCH;
    const int c   = blk - b * NCH;
    const int av  = threadIdx.x;             // 0..191
    const float* p = in + ((size_t)(b * Sn + c * SCHUNK)) * AV + av;
    float acc = 0.f;
    #pragma unroll
    for (int s = 0; s < SCHUNK; ++s) acc += p[(size_t)s * AV];
    partial[(size_t)blk * AV + av] = acc;
}

// ---- corr: one block per (b, 32-t chunk, i-quarter); b = bid%8 (XCD-local) ----
__global__ __launch_bounds__(192)
void corr_kernel(const float* __restrict__ in, const float* __restrict__ partial,
                 float* __restrict__ out) {
    __shared__ __align__(16) float xw[MAXROWS * AV];  // 31.5 KB
    __shared__ __align__(16) float smu[AV];

    const int bid     = blockIdx.x;
    const int b       = bid & 7;             // XCD k <- batch k (bid%8 round-robin)
    const int rem     = bid >> 3;            // 0..63
    const int chunk   = rem >> 2;            // ISPLIT == 4
    const int quarter = rem & 3;
    const int i0      = quarter * ROWS;

    const int t0 = chunk * CH;
    const int t1 = min(t0 + CH - 1, Tn - 1);
    int sbase = t0 - (WIN - 1); if (sbase < 0) sbase = 0;
    const int nrows = t1 - sbase + 1;        // <= 41

    const int tid = threadIdx.x;

    // --- reduce 16 partials -> mean, in LDS ---
    {
        const float* pp = partial + (size_t)b * NCH * AV + tid;
        float acc = 0.f;
        #pragma unroll
        for (int c = 0; c < NCH; ++c) acc += pp[(size_t)c * AV];
        smu[tid] = acc * (1.0f / Sn);
    }
    __syncthreads();

    // --- stage rows [sbase..t1], centered, float4-vectorized ---
    {
        const float4* src = reinterpret_cast<const float4*>(
            in + ((size_t)(b * Sn + sbase)) * AV);
        const float4* mb4 = reinterpret_cast<const float4*>(smu);
        float4* dst = reinterpret_cast<float4*>(xw);
        const int tot4 = nrows * (AV / 4);
        for (int idx = tid; idx < tot4; idx += NTHR) {
            int av4 = idx % (AV / 4);
            float4 v = src[idx], m = mb4[av4];
            v.x -= m.x; v.y -= m.y; v.z -= m.z; v.w -= m.w;
            dst[idx] = v;
        }
    }
    __syncthreads();

    const int tx = tid % TXN;   // float4 col: j = 4*tx + c
    const int ty = tid / TXN;   // row group: i = i0 + ty + 8*r

    float acc[RPT][4];
    float di[RPT], dj[4];
    #pragma unroll
    for (int r = 0; r < RPT; ++r) {
        di[r] = 0.f;
        #pragma unroll
        for (int c = 0; c < 4; ++c) acc[r][c] = 0.f;
    }
    #pragma unroll
    for (int c = 0; c < 4; ++c) dj[c] = 0.f;

#define ACCUM(ls, OP)                                                        \
    {                                                                        \
        const float* xs = &xw[(ls) * AV];                                    \
        float4 xj0 = *reinterpret_cast<const float4*>(&xs[8 * tx]);          \
        float4 xj1 = *reinterpret_cast<const float4*>(&xs[8 * tx + 4]);      \
        dj[0] OP (xj0.x * xj0.x + xj0.y * xj0.y);                            \
        dj[1] OP (xj0.z * xj0.z + xj0.w * xj0.w);                            \
        dj[2] OP (xj1.x * xj1.x + xj1.y * xj1.y);                            \
        dj[3] OP (xj1.z * xj1.z + xj1.w * xj1.w);                            \
        _Pragma("unroll")                                                    \
        for (int r = 0; r < RPT; ++r) {                                      \
            float2 xi = *reinterpret_cast<const float2*>(                    \
                &xs[(i0 + ty + 8 * r) * 2]);                                 \
            di[r] OP (xi.x * xi.x + xi.y * xi.y);                            \
            acc[r][0] OP (xi.x * xj0.x + xi.y * xj0.y);                      \
            acc[r][1] OP (xi.x * xj0.z + xi.y * xj0.w);                      \
            acc[r][2] OP (xi.x * xj1.x + xi.y * xj1.y);                      \
            acc[r][3] OP (xi.x * xj1.z + xi.y * xj1.w);                      \
        }                                                                    \
    }

    // normalize + mask + store one t (one float4 store per r, 1KB/wave-instr)
    auto emit = [&](int t) {
        float rsj[4];
        #pragma unroll
        for (int c = 0; c < 4; ++c) rsj[c] = rsqrtf(dj[c]);
        float* ob = out + (size_t)(b * Tn + t) * (An * An);
        #pragma unroll
        for (int r = 0; r < RPT; ++r) {
            int i = i0 + ty + 8 * r;
            float ri = rsqrtf(di[r]);
            float4 v;
            v.x = (i == 4 * tx + 0) ? 0.f : acc[r][0] * ri * rsj[0];
            v.y = (i == 4 * tx + 1) ? 0.f : acc[r][1] * ri * rsj[1];
            v.z = (i == 4 * tx + 2) ? 0.f : acc[r][2] * ri * rsj[2];
            v.w = (i == 4 * tx + 3) ? 0.f : acc[r][3] * ri * rsj[3];
            *reinterpret_cast<float4*>(&ob[(size_t)i * An + 4 * tx]) = v;
        }
    };

    // --- warm-up: full window sum for t0 ---
    for (int s = sbase; s <= t0; ++s) ACCUM(s - sbase, +=);
    emit(t0);

    // --- slide: W(t) = W(t-1) + g(t) - g(t-WIN) ---
    for (int t = t0 + 1; t <= t1; ++t) {
        ACCUM(t - sbase, +=);
        if (t >= WIN) ACCUM(t - WIN - sbase, -=);
        emit(t);
    }
#undef ACCUM
}

extern "C" void kernel_launch(void* const* d_in, const int* in_sizes, int n_in,
                              void* d_out, int out_size, void* d_ws, size_t ws_size,
                              hipStream_t stream) {
    const float* in = (const float*)d_in[0];
    float* out = (float*)d_out;
    float* partial = (float*)d_ws;    // Bn*NCH*AV = 24576 floats

    partial_kernel<<<Bn * NCH, 192, 0, stream>>>(in, partial);
    corr_kernel<<<Bn * CHUNKS_PER_B * ISPLIT, NTHR, 0, stream>>>(in, partial, out);
}

// Round 10
// 41.514 us; speedup vs baseline: 1.0804x; 1.0140x over previous
//
#include <hip/hip_runtime.h>

// inputs (8, 512, 96, 2) f32, WIN=10. Output (8, 511, 96, 96) f32 = 150.7 MB.
constexpr int WIN = 10;
constexpr int Bn  = 8;
constexpr int Sn  = 512;
constexpr int An  = 96;
constexpr int Tn  = Sn - 1;          // 511
constexpr int AV  = An * 2;          // 192

constexpr int SCHUNK = 32;           // s-rows per partial-sum block
constexpr int NCH    = Sn / SCHUNK;  // 16
constexpr int CH     = 8;            // t-outputs per corr block
constexpr int CHUNKS_PER_B = (Tn + CH - 1) / CH;   // 64
constexpr int MAXROWS = CH + WIN - 1;              // 17 staged s-rows
constexpr int NTHR    = 192;
constexpr int TXN     = 24;          // float4-column index 0..23  (j = 4*tx+c)
constexpr int TYN     = NTHR / TXN;  // 8
constexpr int RPT     = An / TYN;    // 12 rows per thread (full 96 rows/block)

// ---- mean pass: partial sums over 32-s chunks (coalesced) ----
__global__ __launch_bounds__(192)
void partial_kernel(const float* __restrict__ in, float* __restrict__ partial) {
    const int blk = blockIdx.x;              // b * NCH + c
    const int b   = blk / NCH;
    const int c   = blk - b * NCH;
    const int av  = threadIdx.x;             // 0..191
    const float* p = in + ((size_t)(b * Sn + c * SCHUNK)) * AV + av;
    float acc = 0.f;
    #pragma unroll
    for (int s = 0; s < SCHUNK; ++s) acc += p[(size_t)s * AV];
    partial[(size_t)blk * AV + av] = acc;
}

// ---- corr: one block per (b, 8-t chunk); block writes ONE contiguous
// ---- 288 KB output region front-to-back (sequential write stream) ----
__global__ __launch_bounds__(NTHR)
void corr_kernel(const float* __restrict__ in, const float* __restrict__ partial,
                 float* __restrict__ out) {
    __shared__ __align__(16) float xw[MAXROWS * AV];  // 13056 B
    __shared__ __align__(16) float smu[AV];

    const int bid   = blockIdx.x;
    const int b     = bid >> 6;              // bid / CHUNKS_PER_B
    const int chunk = bid & 63;

    const int t0 = chunk * CH;
    const int t1 = min(t0 + CH - 1, Tn - 1);
    int sbase = t0 - (WIN - 1); if (sbase < 0) sbase = 0;
    const int nrows = t1 - sbase + 1;        // <= 17

    const int tid = threadIdx.x;

    // --- reduce 16 partials -> mean, in LDS ---
    {
        const float* pp = partial + (size_t)b * NCH * AV + tid;
        float acc = 0.f;
        #pragma unroll
        for (int c = 0; c < NCH; ++c) acc += pp[(size_t)c * AV];
        smu[tid] = acc * (1.0f / Sn);
    }
    __syncthreads();

    // --- stage rows [sbase..t1], centered, float4-vectorized ---
    {
        const float4* src = reinterpret_cast<const float4*>(
            in + ((size_t)(b * Sn + sbase)) * AV);
        const float4* mb4 = reinterpret_cast<const float4*>(smu);
        float4* dst = reinterpret_cast<float4*>(xw);
        const int tot4 = nrows * (AV / 4);
        for (int idx = tid; idx < tot4; idx += NTHR) {
            int av4 = idx % (AV / 4);
            float4 v = src[idx], m = mb4[av4];
            v.x -= m.x; v.y -= m.y; v.z -= m.z; v.w -= m.w;
            dst[idx] = v;
        }
    }
    __syncthreads();

    const int tx = tid % TXN;   // float4 col: j = 4*tx + c
    const int ty = tid / TXN;   // row group: i = ty + 8*r, r = 0..11

    float acc[RPT][4];
    float di[RPT], dj[4];
    #pragma unroll
    for (int r = 0; r < RPT; ++r) {
        di[r] = 0.f;
        #pragma unroll
        for (int c = 0; c < 4; ++c) acc[r][c] = 0.f;
    }
    #pragma unroll
    for (int c = 0; c < 4; ++c) dj[c] = 0.f;

#define ACCUM(ls, OP)                                                        \
    {                                                                        \
        const float* xs = &xw[(ls) * AV];                                    \
        float4 xj0 = *reinterpret_cast<const float4*>(&xs[8 * tx]);          \
        float4 xj1 = *reinterpret_cast<const float4*>(&xs[8 * tx + 4]);      \
        dj[0] OP (xj0.x * xj0.x + xj0.y * xj0.y);                            \
        dj[1] OP (xj0.z * xj0.z + xj0.w * xj0.w);                            \
        dj[2] OP (xj1.x * xj1.x + xj1.y * xj1.y);                            \
        dj[3] OP (xj1.z * xj1.z + xj1.w * xj1.w);                            \
        _Pragma("unroll")                                                    \
        for (int r = 0; r < RPT; ++r) {                                      \
            float2 xi = *reinterpret_cast<const float2*>(                    \
                &xs[(ty + 8 * r) * 2]);                                      \
            di[r] OP (xi.x * xi.x + xi.y * xi.y);                            \
            acc[r][0] OP (xi.x * xj0.x + xi.y * xj0.y);                      \
            acc[r][1] OP (xi.x * xj0.z + xi.y * xj0.w);                      \
            acc[r][2] OP (xi.x * xj1.x + xi.y * xj1.y);                      \
            acc[r][3] OP (xi.x * xj1.z + xi.y * xj1.w);                      \
        }                                                                    \
    }

    // normalize + mask + store one t: 12 back-to-back float4 stores/thread,
    // block covers the full contiguous 36 KB t-slice; consecutive t adjacent.
    auto emit = [&](int t) {
        float rsj[4];
        #pragma unroll
        for (int c = 0; c < 4; ++c) rsj[c] = rsqrtf(dj[c]);
        float* ob = out + (size_t)(b * Tn + t) * (An * An);
        #pragma unroll
        for (int r = 0; r < RPT; ++r) {
            int i = ty + 8 * r;
            float ri = rsqrtf(di[r]);
            float4 v;
            v.x = (i == 4 * tx + 0) ? 0.f : acc[r][0] * ri * rsj[0];
            v.y = (i == 4 * tx + 1) ? 0.f : acc[r][1] * ri * rsj[1];
            v.z = (i == 4 * tx + 2) ? 0.f : acc[r][2] * ri * rsj[2];
            v.w = (i == 4 * tx + 3) ? 0.f : acc[r][3] * ri * rsj[3];
            *reinterpret_cast<float4*>(&ob[(size_t)i * An + 4 * tx]) = v;
        }
    };

    // --- warm-up: full window sum for t0 ---
    for (int s = sbase; s <= t0; ++s) ACCUM(s - sbase, +=);
    emit(t0);

    // --- slide: W(t) = W(t-1) + g(t) - g(t-WIN) ---
    for (int t = t0 + 1; t <= t1; ++t) {
        ACCUM(t - sbase, +=);
        if (t >= WIN) ACCUM(t - WIN - sbase, -=);
        emit(t);
    }
#undef ACCUM
}

extern "C" void kernel_launch(void* const* d_in, const int* in_sizes, int n_in,
                              void* d_out, int out_size, void* d_ws, size_t ws_size,
                              hipStream_t stream) {
    const float* in = (const float*)d_in[0];
    float* out = (float*)d_out;
    float* partial = (float*)d_ws;    // Bn*NCH*AV = 24576 floats

    partial_kernel<<<Bn * NCH, 192, 0, stream>>>(in, partial);
    corr_kernel<<<Bn * CHUNKS_PER_B, NTHR, 0, stream>>>(in, partial, out);
}

// Round 11
// 41.386 us; speedup vs baseline: 1.0838x; 1.0031x over previous
//
#include <hip/hip_runtime.h>

// inputs (8, 512, 96, 2) f32, WIN=10. Output (8, 511, 96, 96) f32 = 150.7 MB.
constexpr int WIN = 10;
constexpr int Bn  = 8;
constexpr int Sn  = 512;
constexpr int An  = 96;
constexpr int Tn  = Sn - 1;          // 511
constexpr int AV  = An * 2;          // 192

constexpr int SCHUNK = 32;           // s-rows per partial-sum block
constexpr int NCH    = Sn / SCHUNK;  // 16
constexpr int CH     = 16;           // t-outputs per corr block
constexpr int CHUNKS_PER_B = (Tn + CH - 1) / CH;   // 32
constexpr int MAXROWS = CH + WIN - 1;              // 25 staged s-rows
constexpr int ISPLIT  = 4;                         // i-rows split across blocks
constexpr int ROWS    = An / ISPLIT;               // 24 rows per block
constexpr int NTHR    = 192;
constexpr int TXN     = 24;          // float4-column index 0..23  (j = 4*tx+c)
constexpr int TYN     = NTHR / TXN;  // 8
constexpr int RPT     = ROWS / TYN;  // 3 rows per thread

// ---- mean pass: partial sums over 32-s chunks (coalesced) ----
__global__ __launch_bounds__(192)
void partial_kernel(const float* __restrict__ in, float* __restrict__ partial) {
    const int blk = blockIdx.x;              // b * NCH + c
    const int b   = blk / NCH;
    const int c   = blk - b * NCH;
    const int av  = threadIdx.x;             // 0..191
    const float* p = in + ((size_t)(b * Sn + c * SCHUNK)) * AV + av;
    float acc = 0.f;
    #pragma unroll
    for (int s = 0; s < SCHUNK; ++s) acc += p[(size_t)s * AV];
    partial[(size_t)blk * AV + av] = acc;
}

// ---- corr: one block per (b, 16-t chunk, i-quarter), phase-staggered ----
__global__ __launch_bounds__(192)
void corr_kernel(const float* __restrict__ in, const float* __restrict__ partial,
                 float* __restrict__ out) {
    __shared__ __align__(16) float xw[MAXROWS * AV];  // 18.75 KB
    __shared__ __align__(16) float smu[AV];

    const int bid     = blockIdx.x;

    // --- desync: stagger block start to break device-wide store-burst
    // --- lockstep. Slot mixes across-generation bits (bid>>8, co-resident
    // --- on one CU) and across-CU bits (bid low). 0..15 x ~256cy = 0..1.6us.
    {
        int slot = ((bid >> 8) & 3) | ((bid & 3) << 2);
        for (int k = 0; k < slot; ++k) __builtin_amdgcn_s_sleep(4);
    }

    const int b       = bid / (CHUNKS_PER_B * ISPLIT);
    const int rem     = bid - b * (CHUNKS_PER_B * ISPLIT);
    const int chunk   = rem >> 2;            // ISPLIT == 4
    const int quarter = rem & 3;
    const int i0      = quarter * ROWS;

    const int t0 = chunk * CH;
    const int t1 = min(t0 + CH - 1, Tn - 1);
    int sbase = t0 - (WIN - 1); if (sbase < 0) sbase = 0;
    const int nrows = t1 - sbase + 1;        // <= 25

    const int tid = threadIdx.x;

    // --- reduce 16 partials -> mean, in LDS ---
    {
        const float* pp = partial + (size_t)b * NCH * AV + tid;
        float acc = 0.f;
        #pragma unroll
        for (int c = 0; c < NCH; ++c) acc += pp[(size_t)c * AV];
        smu[tid] = acc * (1.0f / Sn);
    }
    __syncthreads();

    // --- stage rows [sbase..t1], centered, float4-vectorized ---
    {
        const float4* src = reinterpret_cast<const float4*>(
            in + ((size_t)(b * Sn + sbase)) * AV);
        const float4* mb4 = reinterpret_cast<const float4*>(smu);
        float4* dst = reinterpret_cast<float4*>(xw);
        const int tot4 = nrows * (AV / 4);
        for (int idx = tid; idx < tot4; idx += NTHR) {
            int av4 = idx % (AV / 4);
            float4 v = src[idx], m = mb4[av4];
            v.x -= m.x; v.y -= m.y; v.z -= m.z; v.w -= m.w;
            dst[idx] = v;
        }
    }
    __syncthreads();

    const int tx = tid % TXN;   // float4 col: j = 4*tx + c
    const int ty = tid / TXN;   // row group: i = i0 + ty + 8*r

    float acc[RPT][4];
    float di[RPT], dj[4];
    #pragma unroll
    for (int r = 0; r < RPT; ++r) {
        di[r] = 0.f;
        #pragma unroll
        for (int c = 0; c < 4; ++c) acc[r][c] = 0.f;
    }
    #pragma unroll
    for (int c = 0; c < 4; ++c) dj[c] = 0.f;

#define ACCUM(ls, OP)                                                        \
    {                                                                        \
        const float* xs = &xw[(ls) * AV];                                    \
        float4 xj0 = *reinterpret_cast<const float4*>(&xs[8 * tx]);          \
        float4 xj1 = *reinterpret_cast<const float4*>(&xs[8 * tx + 4]);      \
        dj[0] OP (xj0.x * xj0.x + xj0.y * xj0.y);                            \
        dj[1] OP (xj0.z * xj0.z + xj0.w * xj0.w);                            \
        dj[2] OP (xj1.x * xj1.x + xj1.y * xj1.y);                            \
        dj[3] OP (xj1.z * xj1.z + xj1.w * xj1.w);                            \
        _Pragma("unroll")                                                    \
        for (int r = 0; r < RPT; ++r) {                                      \
            float2 xi = *reinterpret_cast<const float2*>(                    \
                &xs[(i0 + ty + 8 * r) * 2]);                                 \
            di[r] OP (xi.x * xi.x + xi.y * xi.y);                            \
            acc[r][0] OP (xi.x * xj0.x + xi.y * xj0.y);                      \
            acc[r][1] OP (xi.x * xj0.z + xi.y * xj0.w);                      \
            acc[r][2] OP (xi.x * xj1.x + xi.y * xj1.y);                      \
            acc[r][3] OP (xi.x * xj1.z + xi.y * xj1.w);                      \
        }                                                                    \
    }

    // normalize + mask + store one t (one float4 store per r, 1KB/wave-instr)
    auto emit = [&](int t) {
        float rsj[4];
        #pragma unroll
        for (int c = 0; c < 4; ++c) rsj[c] = rsqrtf(dj[c]);
        float* ob = out + (size_t)(b * Tn + t) * (An * An);
        #pragma unroll
        for (int r = 0; r < RPT; ++r) {
            int i = i0 + ty + 8 * r;
            float ri = rsqrtf(di[r]);
            float4 v;
            v.x = (i == 4 * tx + 0) ? 0.f : acc[r][0] * ri * rsj[0];
            v.y = (i == 4 * tx + 1) ? 0.f : acc[r][1] * ri * rsj[1];
            v.z = (i == 4 * tx + 2) ? 0.f : acc[r][2] * ri * rsj[2];
            v.w = (i == 4 * tx + 3) ? 0.f : acc[r][3] * ri * rsj[3];
            *reinterpret_cast<float4*>(&ob[(size_t)i * An + 4 * tx]) = v;
        }
    };

    // --- warm-up: full window sum for t0 ---
    for (int s = sbase; s <= t0; ++s) ACCUM(s - sbase, +=);
    emit(t0);

    // --- slide: W(t) = W(t-1) + g(t) - g(t-WIN) ---
    for (int t = t0 + 1; t <= t1; ++t) {
        ACCUM(t - sbase, +=);
        if (t >= WIN) ACCUM(t - WIN - sbase, -=);
        emit(t);
    }
#undef ACCUM
}

extern "C" void kernel_launch(void* const* d_in, const int* in_sizes, int n_in,
                              void* d_out, int out_size, void* d_ws, size_t ws_size,
                              hipStream_t stream) {
    const float* in = (const float*)d_in[0];
    float* out = (float*)d_out;
    float* partial = (float*)d_ws;    // Bn*NCH*AV = 24576 floats

    partial_kernel<<<Bn * NCH, 192, 0, stream>>>(in, partial);
    corr_kernel<<<Bn * CHUNKS_PER_B * ISPLIT, NTHR, 0, stream>>>(in, partial, out);
}